// Round 1
// baseline (2458.536 us; speedup 1.0000x reference)
//
#include <hip/hip_runtime.h>
#include <math.h>

// ---------------------------------------------------------------------------
// Temporal GNN: FT-GEMM+ReLU -> LN+PE -> 3x(GCN GEMM + CSR aggregate) ->
// mean-pool -> MLP. All fp32 (threshold 2.4e-4 forbids plain bf16).
// ---------------------------------------------------------------------------

// GEMM: C[M x 256] = A[M x 256] @ B[256 x 256], optional bias/rowscale/relu.
// BM=64 rows x all 256 cols, BK=16, 256 threads, 4x16 micro-tile per thread.
__global__ __launch_bounds__(256, 4)
void tg_gemm256(const float* __restrict__ A, const float* __restrict__ B,
                const float* __restrict__ bias, const float* __restrict__ rowscale,
                float* __restrict__ C, int M, int do_relu)
{
    __shared__ float As[16][68];   // [k][m], +4 pad keeps 16B align & kills conflicts
    __shared__ float Bs[16][256];  // [k][n]
    const int t  = threadIdx.x;
    const int tx = t & 15;
    const int ty = t >> 4;
    const int row0 = blockIdx.x * 64;

    float acc[4][16];
#pragma unroll
    for (int r = 0; r < 4; ++r)
#pragma unroll
        for (int c = 0; c < 16; ++c) acc[r][c] = 0.f;

    const int arow = t >> 2;          // 0..63
    const int acol = (t & 3) << 2;    // 0,4,8,12
    const int brow = t >> 4;          // 0..15
    const int bcol = (t & 15) << 2;   // 0..60
    const bool avalid = (row0 + arow) < M;
    const float* Ap = A + (size_t)(row0 + arow) * 256 + acol;

    for (int kt = 0; kt < 16; ++kt) {
        float4 a4 = make_float4(0.f, 0.f, 0.f, 0.f);
        if (avalid) a4 = *(const float4*)(Ap + kt * 16);
        float4 b4[4];
        const float* Bp = B + (size_t)(kt * 16 + brow) * 256 + bcol;
#pragma unroll
        for (int j = 0; j < 4; ++j) b4[j] = *(const float4*)(Bp + 64 * j);

        __syncthreads();
        As[acol + 0][arow] = a4.x;
        As[acol + 1][arow] = a4.y;
        As[acol + 2][arow] = a4.z;
        As[acol + 3][arow] = a4.w;
#pragma unroll
        for (int j = 0; j < 4; ++j)
            *(float4*)&Bs[brow][bcol + 64 * j] = b4[j];
        __syncthreads();

#pragma unroll
        for (int k = 0; k < 16; ++k) {
            const float4 av = *(const float4*)&As[k][ty << 2];
            const float ar[4] = {av.x, av.y, av.z, av.w};
#pragma unroll
            for (int j = 0; j < 4; ++j) {
                const float4 bv = *(const float4*)&Bs[k][(tx << 2) + 64 * j];
                const float br[4] = {bv.x, bv.y, bv.z, bv.w};
#pragma unroll
                for (int r = 0; r < 4; ++r)
#pragma unroll
                    for (int i = 0; i < 4; ++i)
                        acc[r][j * 4 + i] += ar[r] * br[i];
            }
        }
    }

#pragma unroll
    for (int r = 0; r < 4; ++r) {
        const int gr = row0 + (ty << 2) + r;
        if (gr >= M) continue;
        const float s = rowscale ? rowscale[gr] : 1.f;
#pragma unroll
        for (int j = 0; j < 4; ++j) {
            const int c = (tx << 2) + 64 * j;
            float4 o;
            o.x = acc[r][j * 4 + 0] * s;
            o.y = acc[r][j * 4 + 1] * s;
            o.z = acc[r][j * 4 + 2] * s;
            o.w = acc[r][j * 4 + 3] * s;
            if (bias) {
                const float4 bb = *(const float4*)&bias[c];
                o.x += bb.x; o.y += bb.y; o.z += bb.z; o.w += bb.w;
            }
            if (do_relu) {
                o.x = fmaxf(o.x, 0.f); o.y = fmaxf(o.y, 0.f);
                o.z = fmaxf(o.z, 0.f); o.w = fmaxf(o.w, 0.f);
            }
            *(float4*)&C[(size_t)gr * 256 + c] = o;
        }
    }
}

// LayerNorm (in-place) + sinusoidal PE. One wave per row, 4 cols/lane.
__global__ void tg_ln_pe(float* __restrict__ h, const float* __restrict__ g,
                         const float* __restrict__ b, int N)
{
    const int gt = blockIdx.x * blockDim.x + threadIdx.x;
    const int row = gt >> 6;
    const int lane = threadIdx.x & 63;
    if (row >= N) return;
    float* hp = h + (size_t)row * 256 + lane * 4;
    float4 v = *(float4*)hp;
    float s = v.x + v.y + v.z + v.w;
#pragma unroll
    for (int m = 1; m < 64; m <<= 1) s += __shfl_xor(s, m, 64);
    const float mu = s * (1.f / 256.f);
    const float d0 = v.x - mu, d1 = v.y - mu, d2 = v.z - mu, d3 = v.w - mu;
    float q = d0 * d0 + d1 * d1 + d2 * d2 + d3 * d3;
#pragma unroll
    for (int m = 1; m < 64; m <<= 1) q += __shfl_xor(q, m, 64);
    const float rstd = 1.f / sqrtf(q * (1.f / 256.f) + 1e-5f);

    const int c = lane * 4;
    const float4 gg = *(const float4*)&g[c];
    const float4 bb = *(const float4*)&b[c];
    // pe[n,2j]=sin(n*div_j), pe[n,2j+1]=cos(n*div_j), div_j=exp(2j * -ln(1e4)/256)
    // cols c,c+1 -> 2j=c ; cols c+2,c+3 -> 2j=c+2   (fp32 to match reference rounding)
    const float cexp = -0.035977892078031970f;  // -log(10000)/256 (double, rounded)
    const float fn = (float)row;
    const float div0 = expf((float)c * cexp);
    const float div1 = expf((float)(c + 2) * cexp);
    const float a0 = fn * div0;
    const float a1 = fn * div1;
    float4 o;
    o.x = d0 * rstd * gg.x + bb.x + sinf(a0);
    o.y = d1 * rstd * gg.y + bb.y + cosf(a0);
    o.z = d2 * rstd * gg.z + bb.z + sinf(a1);
    o.w = d3 * rstd * gg.w + bb.w + cosf(a1);
    *(float4*)hp = o;
}

__global__ void tg_count(const int* __restrict__ dst, int* __restrict__ deg, int E)
{
    const int e = blockIdx.x * blockDim.x + threadIdx.x;
    if (e < E) atomicAdd(&deg[dst[e]], 1);
}

__global__ void tg_dinv(const int* __restrict__ deg, float* __restrict__ dinv, int N)
{
    const int i = blockIdx.x * blockDim.x + threadIdx.x;
    if (i < N) dinv[i] = 1.f / sqrtf((float)(deg[i] + 1));  // +1 self-loop
}

// Hierarchical exclusive scan of deg -> rowptr.
__global__ void tg_scan1(const int* __restrict__ cnt, int* __restrict__ out,
                         int* __restrict__ sums, int N)
{
    __shared__ int tmp[1024];
    const int t = threadIdx.x;
    const int gid = blockIdx.x * 1024 + t;
    const int v = (gid < N) ? cnt[gid] : 0;
    tmp[t] = v;
    __syncthreads();
    for (int o = 1; o < 1024; o <<= 1) {
        const int add = (t >= o) ? tmp[t - o] : 0;
        __syncthreads();
        tmp[t] += add;
        __syncthreads();
    }
    if (gid < N) out[gid] = tmp[t] - v;  // exclusive
    if (t == 1023) sums[blockIdx.x] = tmp[t];
}

__global__ void tg_scan2(int* __restrict__ sums, int nb)
{
    __shared__ int tmp[1024];
    const int t = threadIdx.x;
    const int v = (t < nb) ? sums[t] : 0;
    tmp[t] = v;
    __syncthreads();
    for (int o = 1; o < 1024; o <<= 1) {
        const int add = (t >= o) ? tmp[t - o] : 0;
        __syncthreads();
        tmp[t] += add;
        __syncthreads();
    }
    if (t < nb) sums[t] = tmp[t] - v;  // exclusive block offsets
}

__global__ void tg_scan3(int* __restrict__ rowptr, const int* __restrict__ offs,
                         int N, int E)
{
    const int gid = blockIdx.x * 1024 + threadIdx.x;
    if (gid < N) rowptr[gid] += offs[gid >> 10];
    else if (gid == N) rowptr[N] = E;
}

__global__ void tg_fill(const int* __restrict__ src, const int* __restrict__ dst,
                        const int* __restrict__ rowptr, int* __restrict__ cursor,
                        int* __restrict__ col, int E)
{
    const int e = blockIdx.x * blockDim.x + threadIdx.x;
    if (e >= E) return;
    const int d = dst[e];
    const int p = atomicAdd(&cursor[d], 1);
    col[rowptr[d] + p] = src[e];
}

// out[i] = relu(dinv[i] * (hwp[i] + sum_{src in row i} hwp[src]) + bias)
// One wave per node, 4 cols/lane, neighbor loop unrolled x4 for MLP latency.
__global__ void tg_aggregate(const float* __restrict__ hwp, const int* __restrict__ rowptr,
                             const int* __restrict__ col, const float* __restrict__ dinv,
                             const float* __restrict__ bias, float* __restrict__ out, int N)
{
    const int gt = blockIdx.x * blockDim.x + threadIdx.x;
    const int row = gt >> 6;
    const int lane = threadIdx.x & 63;
    if (row >= N) return;
    const int c = lane * 4;
    const float* base = hwp + c;
    float4 acc = *(const float4*)&hwp[(size_t)row * 256 + c];
    const int beg = rowptr[row], end = rowptr[row + 1];
    int p = beg;
    for (; p + 4 <= end; p += 4) {
        const int j0 = col[p], j1 = col[p + 1], j2 = col[p + 2], j3 = col[p + 3];
        const float4 v0 = *(const float4*)(base + (size_t)j0 * 256);
        const float4 v1 = *(const float4*)(base + (size_t)j1 * 256);
        const float4 v2 = *(const float4*)(base + (size_t)j2 * 256);
        const float4 v3 = *(const float4*)(base + (size_t)j3 * 256);
        acc.x += v0.x + v1.x + v2.x + v3.x;
        acc.y += v0.y + v1.y + v2.y + v3.y;
        acc.z += v0.z + v1.z + v2.z + v3.z;
        acc.w += v0.w + v1.w + v2.w + v3.w;
    }
    for (; p < end; ++p) {
        const int j = col[p];
        const float4 v = *(const float4*)(base + (size_t)j * 256);
        acc.x += v.x; acc.y += v.y; acc.z += v.z; acc.w += v.w;
    }
    const float di = dinv[row];
    const float4 bb = *(const float4*)&bias[c];
    float4 o;
    o.x = fmaxf(di * acc.x + bb.x, 0.f);
    o.y = fmaxf(di * acc.y + bb.y, 0.f);
    o.z = fmaxf(di * acc.z + bb.z, 0.f);
    o.w = fmaxf(di * acc.w + bb.w, 0.f);
    *(float4*)&out[(size_t)row * 256 + c] = o;
}

// starts[g] = lower_bound(batch, g), g in [0,G] (batch is sorted)
__global__ void tg_ranges(const int* __restrict__ batch, int* __restrict__ starts,
                          int N, int G)
{
    const int g = blockIdx.x * blockDim.x + threadIdx.x;
    if (g > G) return;
    int lo = 0, hi = N;
    while (lo < hi) {
        const int mid = (lo + hi) >> 1;
        if (batch[mid] < g) lo = mid + 1; else hi = mid;
    }
    starts[g] = lo;
}

__global__ void tg_pool(const float* __restrict__ h, const int* __restrict__ starts,
                        float* __restrict__ pooled, int G)
{
    const int g = blockIdx.x;
    const int c = threadIdx.x;
    const int beg = starts[g], end = starts[g + 1];
    float s = 0.f;
    for (int r = beg; r < end; ++r) s += h[(size_t)r * 256 + c];
    const float cnt = (float)(end - beg);
    pooled[(size_t)g * 256 + c] = s / fmaxf(cnt, 1.f);
}

__global__ void tg_mlp(const float* __restrict__ A, const float* __restrict__ B,
                       const float* __restrict__ bias, float* __restrict__ Cout,
                       int M, int K, int Nc, int do_relu)
{
    const int idx = blockIdx.x * blockDim.x + threadIdx.x;
    if (idx >= M * Nc) return;
    const int m = idx / Nc;
    const int n = idx - m * Nc;
    float acc = 0.f;
    for (int k = 0; k < K; ++k) acc += A[(size_t)m * K + k] * B[(size_t)k * Nc + n];
    acc += bias[n];
    Cout[idx] = do_relu ? fmaxf(acc, 0.f) : acc;
}

extern "C" void kernel_launch(void* const* d_in, const int* in_sizes, int n_in,
                              void* d_out, int out_size, void* d_ws, size_t ws_size,
                              hipStream_t stream)
{
    const float* x    = (const float*)d_in[0];
    const float* W_ft = (const float*)d_in[1];
    const float* b_ft = (const float*)d_in[2];
    const float* ln_g = (const float*)d_in[3];
    const float* ln_b = (const float*)d_in[4];
    const float* W_g[3] = {(const float*)d_in[5], (const float*)d_in[7], (const float*)d_in[9]};
    const float* b_g[3] = {(const float*)d_in[6], (const float*)d_in[8], (const float*)d_in[10]};
    const float* W_c0 = (const float*)d_in[11];
    const float* b_c0 = (const float*)d_in[12];
    const float* W_c1 = (const float*)d_in[13];
    const float* b_c1 = (const float*)d_in[14];
    const float* W_c2 = (const float*)d_in[15];
    const float* b_c2 = (const float*)d_in[16];
    const int*   edge  = (const int*)d_in[17];
    const int*   batch = (const int*)d_in[18];

    const int N  = in_sizes[18];        // 100000
    const int E  = in_sizes[17] / 2;    // 1600000
    const int H2 = in_sizes[14];        // 128
    const int Cc = in_sizes[15] / H2;   // 4
    const int G  = out_size / Cc;       // 512

    const int* srcI = edge;
    const int* dstI = edge + E;

    size_t off = 0;
    auto alloc = [&](size_t bytes) {
        char* p = (char*)d_ws + off;
        off = (off + bytes + 255) & ~(size_t)255;
        return p;
    };
    float* h      = (float*)alloc((size_t)N * 256 * 4);
    float* hwp    = (float*)alloc((size_t)N * 256 * 4);
    float* dinv   = (float*)alloc((size_t)N * 4);
    int*   deg    = (int*)alloc((size_t)N * 4);
    int*   rowptr = (int*)alloc((size_t)(N + 1) * 4);
    int*   cursor = (int*)alloc((size_t)N * 4);
    int*   col    = (int*)alloc((size_t)E * 4);
    int*   bsums  = (int*)alloc(1024 * 4);
    int*   starts = (int*)alloc((size_t)(G + 1) * 4);
    float* pooled = (float*)alloc((size_t)G * 256 * 4);
    float* z0     = (float*)alloc((size_t)G * 256 * 4);
    float* z1     = (float*)alloc((size_t)G * H2 * 4);
    (void)ws_size; (void)n_in;

    hipMemsetAsync(deg, 0, (size_t)N * 4, stream);
    hipMemsetAsync(cursor, 0, (size_t)N * 4, stream);

    // 1. feature transform: h = relu(x @ W_ft + b_ft)
    tg_gemm256<<<dim3((N + 63) / 64), dim3(256), 0, stream>>>(x, W_ft, b_ft, nullptr, h, N, 1);
    // 2. LayerNorm + positional encoding (in place)
    tg_ln_pe<<<dim3((N + 3) / 4), dim3(256), 0, stream>>>(h, ln_g, ln_b, N);
    // 3. degrees + CSR build (rows = dst, cols = src)
    tg_count<<<dim3((E + 255) / 256), dim3(256), 0, stream>>>(dstI, deg, E);
    tg_dinv<<<dim3((N + 255) / 256), dim3(256), 0, stream>>>(deg, dinv, N);
    const int NB = (N + 1023) / 1024;
    tg_scan1<<<dim3(NB), dim3(1024), 0, stream>>>(deg, rowptr, bsums, N);
    tg_scan2<<<dim3(1), dim3(1024), 0, stream>>>(bsums, NB);
    tg_scan3<<<dim3((N + 1024) / 1024), dim3(1024), 0, stream>>>(rowptr, bsums, N, E);
    tg_fill<<<dim3((E + 255) / 256), dim3(256), 0, stream>>>(srcI, dstI, rowptr, cursor, col, E);
    // 4. GCN layers: hwp = (h@W)*dinv[row]; h = relu(dinv*(hwp[i]+sum hwp[src]) + b)
    for (int l = 0; l < 3; ++l) {
        tg_gemm256<<<dim3((N + 63) / 64), dim3(256), 0, stream>>>(h, W_g[l], nullptr, dinv, hwp, N, 0);
        tg_aggregate<<<dim3((N + 3) / 4), dim3(256), 0, stream>>>(hwp, rowptr, col, dinv, b_g[l], h, N);
    }
    // 5. per-graph mean pool
    tg_ranges<<<dim3((G + 256) / 256), dim3(256), 0, stream>>>(batch, starts, N, G);
    tg_pool<<<dim3(G), dim3(256), 0, stream>>>(h, starts, pooled, G);
    // 6. classifier MLP
    tg_mlp<<<dim3((G * 256 + 255) / 256), dim3(256), 0, stream>>>(pooled, W_c0, b_c0, z0, G, 256, 256, 1);
    tg_mlp<<<dim3((G * H2 + 255) / 256), dim3(256), 0, stream>>>(z0, W_c1, b_c1, z1, G, 256, H2, 1);
    tg_mlp<<<dim3((G * Cc + 255) / 256), dim3(256), 0, stream>>>(z1, W_c2, b_c2, (float*)d_out, G, H2, Cc, 0);
}

// Round 2
// 2059.464 us; speedup vs baseline: 1.1938x; 1.1938x over previous
//
#include <hip/hip_runtime.h>
#include <math.h>

// ---------------------------------------------------------------------------
// Temporal GNN. Round 2: GEMMs -> split-bf16 MFMA (hi/lo x3 products, fp32
// accumulate). Everything else unchanged from the passing round-1 kernel.
// ---------------------------------------------------------------------------

typedef __attribute__((ext_vector_type(8))) short short8;   // 8 bf16 (4 VGPR)
typedef __attribute__((ext_vector_type(4))) float floatx4;  // MFMA C/D

static __device__ __forceinline__ unsigned short f2bf(float f) {
    unsigned u = __float_as_uint(f);
    unsigned r = u + 0x7fff + ((u >> 16) & 1);   // RNE
    return (unsigned short)(r >> 16);
}
static __device__ __forceinline__ float bf2f(unsigned short s) {
    return __uint_as_float(((unsigned)s) << 16);
}

// Split W[256][256] (k-major) into transposed bf16 planes Bt_hi/Bt_lo [n][k].
__global__ void tg_splitB(const float* __restrict__ W,
                          unsigned short* __restrict__ Bth,
                          unsigned short* __restrict__ Btl)
{
    __shared__ float T[64][68];
    const int tk = blockIdx.x * 64, tn = blockIdx.y * 64;
    const int t = threadIdx.x;
#pragma unroll
    for (int j = 0; j < 4; ++j) {
        const int idx = t + 256 * j;
        const int k = idx >> 4, c4 = (idx & 15) * 4;
        const float4 v = *(const float4*)&W[(size_t)(tk + k) * 256 + tn + c4];
        T[k][c4] = v.x; T[k][c4 + 1] = v.y; T[k][c4 + 2] = v.z; T[k][c4 + 3] = v.w;
    }
    __syncthreads();
#pragma unroll
    for (int j = 0; j < 4; ++j) {
        const int idx = t + 256 * j;
        const int n = idx >> 4, q = (idx & 15) * 4;
        unsigned short hh[4], ll[4];
#pragma unroll
        for (int i = 0; i < 4; ++i) {
            const float f = T[q + i][n];
            hh[i] = f2bf(f);
            ll[i] = f2bf(f - bf2f(hh[i]));
        }
        uint2 hp, lp;
        hp.x = (unsigned)hh[0] | ((unsigned)hh[1] << 16);
        hp.y = (unsigned)hh[2] | ((unsigned)hh[3] << 16);
        lp.x = (unsigned)ll[0] | ((unsigned)ll[1] << 16);
        lp.y = (unsigned)ll[2] | ((unsigned)ll[3] << 16);
        *(uint2*)&Bth[(size_t)(tn + n) * 256 + tk + q] = hp;
        *(uint2*)&Btl[(size_t)(tn + n) * 256 + tk + q] = lp;
    }
}

// C[M x 256] = A[M x 256] @ B[256 x 256] via split-bf16 MFMA.
// Block: 256 thr (4 waves), BM=64, BN=256 (wave w owns cols 64w..64w+63).
// K in 8 chunks of 32. A staged fp32->hi/lo bf16 in LDS; B pre-split planes.
#define APAD 40
__global__ __launch_bounds__(256, 3)
void tg_gemm_mfma(const float* __restrict__ A,
                  const unsigned short* __restrict__ Bth,
                  const unsigned short* __restrict__ Btl,
                  const float* __restrict__ bias, const float* __restrict__ rowscale,
                  float* __restrict__ C, int M, int do_relu)
{
    __shared__ unsigned short Ah[64][APAD], Al[64][APAD];
    __shared__ unsigned short Bh[256][APAD], Bl[256][APAD];

    const int t = threadIdx.x;
    const int row0 = blockIdx.x * 64;
    const int w = t >> 6, lane = t & 63;
    const int quad = lane >> 4, l16 = lane & 15;

    floatx4 acc[4][4];
#pragma unroll
    for (int i = 0; i < 4; ++i)
#pragma unroll
        for (int j = 0; j < 4; ++j) acc[i][j] = (floatx4){0.f, 0.f, 0.f, 0.f};

    // A staging map: row = t>>2 (0..63), float4 at col (t&3)*4 and +16
    const int s_ar = t >> 2;
    const int s_ac = (t & 3) * 4;
    const bool arow_ok = (row0 + s_ar) < M;
    const float* Arow = A + (size_t)(row0 + s_ar) * 256;

    for (int kc = 0; kc < 8; ++kc) {
        const int k0 = kc * 32;
        // ---- stage A (fp32 -> hi/lo bf16) ----
        float4 av[2];
        av[0] = arow_ok ? *(const float4*)(Arow + k0 + s_ac)
                        : make_float4(0.f, 0.f, 0.f, 0.f);
        av[1] = arow_ok ? *(const float4*)(Arow + k0 + s_ac + 16)
                        : make_float4(0.f, 0.f, 0.f, 0.f);
        // ---- stage B (pre-split bf16 planes, [n][k]) ----
        uint4 bh[4], bl[4];
#pragma unroll
        for (int j = 0; j < 4; ++j) {
            const int idx = t + 256 * j;
            const int n = idx >> 2, q = (idx & 3) * 8;
            bh[j] = *(const uint4*)&Bth[(size_t)n * 256 + k0 + q];
            bl[j] = *(const uint4*)&Btl[(size_t)n * 256 + k0 + q];
        }
        __syncthreads();
#pragma unroll
        for (int h = 0; h < 2; ++h) {
            const float f[4] = {av[h].x, av[h].y, av[h].z, av[h].w};
            unsigned short hh[4], ll[4];
#pragma unroll
            for (int i = 0; i < 4; ++i) {
                hh[i] = f2bf(f[i]);
                ll[i] = f2bf(f[i] - bf2f(hh[i]));
            }
            uint2 hp, lp;
            hp.x = (unsigned)hh[0] | ((unsigned)hh[1] << 16);
            hp.y = (unsigned)hh[2] | ((unsigned)hh[3] << 16);
            lp.x = (unsigned)ll[0] | ((unsigned)ll[1] << 16);
            lp.y = (unsigned)ll[2] | ((unsigned)ll[3] << 16);
            *(uint2*)&Ah[s_ar][s_ac + 16 * h] = hp;
            *(uint2*)&Al[s_ar][s_ac + 16 * h] = lp;
        }
#pragma unroll
        for (int j = 0; j < 4; ++j) {
            const int idx = t + 256 * j;
            const int n = idx >> 2, q = (idx & 3) * 8;
            *(uint4*)&Bh[n][q] = bh[j];
            *(uint4*)&Bl[n][q] = bl[j];
        }
        __syncthreads();

        // ---- fragments ----
        short8 a_hi[4], a_lo[4], b_hi[4], b_lo[4];
#pragma unroll
        for (int rt = 0; rt < 4; ++rt) {
            a_hi[rt] = *(const short8*)&Ah[rt * 16 + l16][quad * 8];
            a_lo[rt] = *(const short8*)&Al[rt * 16 + l16][quad * 8];
        }
#pragma unroll
        for (int ct = 0; ct < 4; ++ct) {
            b_hi[ct] = *(const short8*)&Bh[w * 64 + ct * 16 + l16][quad * 8];
            b_lo[ct] = *(const short8*)&Bl[w * 64 + ct * 16 + l16][quad * 8];
        }
#pragma unroll
        for (int rt = 0; rt < 4; ++rt)
#pragma unroll
            for (int ct = 0; ct < 4; ++ct) {
                acc[rt][ct] = __builtin_amdgcn_mfma_f32_16x16x32_bf16(
                    a_hi[rt], b_hi[ct], acc[rt][ct], 0, 0, 0);
                acc[rt][ct] = __builtin_amdgcn_mfma_f32_16x16x32_bf16(
                    a_lo[rt], b_hi[ct], acc[rt][ct], 0, 0, 0);
                acc[rt][ct] = __builtin_amdgcn_mfma_f32_16x16x32_bf16(
                    a_hi[rt], b_lo[ct], acc[rt][ct], 0, 0, 0);
            }
        __syncthreads();
    }

    // ---- epilogue: C[row][col], row = row0+rt*16+quad*4+i, col = w*64+ct*16+l16
#pragma unroll
    for (int rt = 0; rt < 4; ++rt) {
#pragma unroll
        for (int i = 0; i < 4; ++i) {
            const int gr = row0 + rt * 16 + quad * 4 + i;
            if (gr >= M) continue;
            const float s = rowscale ? rowscale[gr] : 1.f;
#pragma unroll
            for (int ct = 0; ct < 4; ++ct) {
                const int gc = w * 64 + ct * 16 + l16;
                float v = acc[rt][ct][i] * s;
                if (bias) v += bias[gc];
                if (do_relu) v = fmaxf(v, 0.f);
                C[(size_t)gr * 256 + gc] = v;
            }
        }
    }
}

// LayerNorm (in-place) + sinusoidal PE. One wave per row, 4 cols/lane.
__global__ void tg_ln_pe(float* __restrict__ h, const float* __restrict__ g,
                         const float* __restrict__ b, int N)
{
    const int gt = blockIdx.x * blockDim.x + threadIdx.x;
    const int row = gt >> 6;
    const int lane = threadIdx.x & 63;
    if (row >= N) return;
    float* hp = h + (size_t)row * 256 + lane * 4;
    float4 v = *(float4*)hp;
    float s = v.x + v.y + v.z + v.w;
#pragma unroll
    for (int m = 1; m < 64; m <<= 1) s += __shfl_xor(s, m, 64);
    const float mu = s * (1.f / 256.f);
    const float d0 = v.x - mu, d1 = v.y - mu, d2 = v.z - mu, d3 = v.w - mu;
    float q = d0 * d0 + d1 * d1 + d2 * d2 + d3 * d3;
#pragma unroll
    for (int m = 1; m < 64; m <<= 1) q += __shfl_xor(q, m, 64);
    const float rstd = 1.f / sqrtf(q * (1.f / 256.f) + 1e-5f);

    const int c = lane * 4;
    const float4 gg = *(const float4*)&g[c];
    const float4 bb = *(const float4*)&b[c];
    const float cexp = -0.035977892078031970f;  // -log(10000)/256
    const float fn = (float)row;
    const float div0 = expf((float)c * cexp);
    const float div1 = expf((float)(c + 2) * cexp);
    const float a0 = fn * div0;
    const float a1 = fn * div1;
    float4 o;
    o.x = d0 * rstd * gg.x + bb.x + sinf(a0);
    o.y = d1 * rstd * gg.y + bb.y + cosf(a0);
    o.z = d2 * rstd * gg.z + bb.z + sinf(a1);
    o.w = d3 * rstd * gg.w + bb.w + cosf(a1);
    *(float4*)hp = o;
}

__global__ void tg_count(const int* __restrict__ dst, int* __restrict__ deg, int E)
{
    const int e = blockIdx.x * blockDim.x + threadIdx.x;
    if (e < E) atomicAdd(&deg[dst[e]], 1);
}

__global__ void tg_dinv(const int* __restrict__ deg, float* __restrict__ dinv, int N)
{
    const int i = blockIdx.x * blockDim.x + threadIdx.x;
    if (i < N) dinv[i] = 1.f / sqrtf((float)(deg[i] + 1));  // +1 self-loop
}

__global__ void tg_scan1(const int* __restrict__ cnt, int* __restrict__ out,
                         int* __restrict__ sums, int N)
{
    __shared__ int tmp[1024];
    const int t = threadIdx.x;
    const int gid = blockIdx.x * 1024 + t;
    const int v = (gid < N) ? cnt[gid] : 0;
    tmp[t] = v;
    __syncthreads();
    for (int o = 1; o < 1024; o <<= 1) {
        const int add = (t >= o) ? tmp[t - o] : 0;
        __syncthreads();
        tmp[t] += add;
        __syncthreads();
    }
    if (gid < N) out[gid] = tmp[t] - v;
    if (t == 1023) sums[blockIdx.x] = tmp[t];
}

__global__ void tg_scan2(int* __restrict__ sums, int nb)
{
    __shared__ int tmp[1024];
    const int t = threadIdx.x;
    const int v = (t < nb) ? sums[t] : 0;
    tmp[t] = v;
    __syncthreads();
    for (int o = 1; o < 1024; o <<= 1) {
        const int add = (t >= o) ? tmp[t - o] : 0;
        __syncthreads();
        tmp[t] += add;
        __syncthreads();
    }
    if (t < nb) sums[t] = tmp[t] - v;
}

__global__ void tg_scan3(int* __restrict__ rowptr, const int* __restrict__ offs,
                         int N, int E)
{
    const int gid = blockIdx.x * 1024 + threadIdx.x;
    if (gid < N) rowptr[gid] += offs[gid >> 10];
    else if (gid == N) rowptr[N] = E;
}

__global__ void tg_fill(const int* __restrict__ src, const int* __restrict__ dst,
                        const int* __restrict__ rowptr, int* __restrict__ cursor,
                        int* __restrict__ col, int E)
{
    const int e = blockIdx.x * blockDim.x + threadIdx.x;
    if (e >= E) return;
    const int d = dst[e];
    const int p = atomicAdd(&cursor[d], 1);
    col[rowptr[d] + p] = src[e];
}

// out[i] = relu(dinv[i] * (hwp[i] + sum_{src in row i} hwp[src]) + bias)
__global__ void tg_aggregate(const float* __restrict__ hwp, const int* __restrict__ rowptr,
                             const int* __restrict__ col, const float* __restrict__ dinv,
                             const float* __restrict__ bias, float* __restrict__ out, int N)
{
    const int gt = blockIdx.x * blockDim.x + threadIdx.x;
    const int row = gt >> 6;
    const int lane = threadIdx.x & 63;
    if (row >= N) return;
    const int c = lane * 4;
    const float* base = hwp + c;
    float4 acc = *(const float4*)&hwp[(size_t)row * 256 + c];
    const int beg = rowptr[row], end = rowptr[row + 1];
    int p = beg;
    for (; p + 4 <= end; p += 4) {
        const int j0 = col[p], j1 = col[p + 1], j2 = col[p + 2], j3 = col[p + 3];
        const float4 v0 = *(const float4*)(base + (size_t)j0 * 256);
        const float4 v1 = *(const float4*)(base + (size_t)j1 * 256);
        const float4 v2 = *(const float4*)(base + (size_t)j2 * 256);
        const float4 v3 = *(const float4*)(base + (size_t)j3 * 256);
        acc.x += v0.x + v1.x + v2.x + v3.x;
        acc.y += v0.y + v1.y + v2.y + v3.y;
        acc.z += v0.z + v1.z + v2.z + v3.z;
        acc.w += v0.w + v1.w + v2.w + v3.w;
    }
    for (; p < end; ++p) {
        const int j = col[p];
        const float4 v = *(const float4*)(base + (size_t)j * 256);
        acc.x += v.x; acc.y += v.y; acc.z += v.z; acc.w += v.w;
    }
    const float di = dinv[row];
    const float4 bb = *(const float4*)&bias[c];
    float4 o;
    o.x = fmaxf(di * acc.x + bb.x, 0.f);
    o.y = fmaxf(di * acc.y + bb.y, 0.f);
    o.z = fmaxf(di * acc.z + bb.z, 0.f);
    o.w = fmaxf(di * acc.w + bb.w, 0.f);
    *(float4*)&out[(size_t)row * 256 + c] = o;
}

__global__ void tg_ranges(const int* __restrict__ batch, int* __restrict__ starts,
                          int N, int G)
{
    const int g = blockIdx.x * blockDim.x + threadIdx.x;
    if (g > G) return;
    int lo = 0, hi = N;
    while (lo < hi) {
        const int mid = (lo + hi) >> 1;
        if (batch[mid] < g) lo = mid + 1; else hi = mid;
    }
    starts[g] = lo;
}

__global__ void tg_pool(const float* __restrict__ h, const int* __restrict__ starts,
                        float* __restrict__ pooled, int G)
{
    const int g = blockIdx.x;
    const int c = threadIdx.x;
    const int beg = starts[g], end = starts[g + 1];
    float s = 0.f;
    for (int r = beg; r < end; ++r) s += h[(size_t)r * 256 + c];
    const float cnt = (float)(end - beg);
    pooled[(size_t)g * 256 + c] = s / fmaxf(cnt, 1.f);
}

__global__ void tg_mlp(const float* __restrict__ A, const float* __restrict__ B,
                       const float* __restrict__ bias, float* __restrict__ Cout,
                       int M, int K, int Nc, int do_relu)
{
    const int idx = blockIdx.x * blockDim.x + threadIdx.x;
    if (idx >= M * Nc) return;
    const int m = idx / Nc;
    const int n = idx - m * Nc;
    float acc = 0.f;
    for (int k = 0; k < K; ++k) acc += A[(size_t)m * K + k] * B[(size_t)k * Nc + n];
    acc += bias[n];
    Cout[idx] = do_relu ? fmaxf(acc, 0.f) : acc;
}

extern "C" void kernel_launch(void* const* d_in, const int* in_sizes, int n_in,
                              void* d_out, int out_size, void* d_ws, size_t ws_size,
                              hipStream_t stream)
{
    const float* x    = (const float*)d_in[0];
    const float* W_ft = (const float*)d_in[1];
    const float* b_ft = (const float*)d_in[2];
    const float* ln_g = (const float*)d_in[3];
    const float* ln_b = (const float*)d_in[4];
    const float* W_g[3] = {(const float*)d_in[5], (const float*)d_in[7], (const float*)d_in[9]};
    const float* b_g[3] = {(const float*)d_in[6], (const float*)d_in[8], (const float*)d_in[10]};
    const float* W_c0 = (const float*)d_in[11];
    const float* b_c0 = (const float*)d_in[12];
    const float* W_c1 = (const float*)d_in[13];
    const float* b_c1 = (const float*)d_in[14];
    const float* W_c2 = (const float*)d_in[15];
    const float* b_c2 = (const float*)d_in[16];
    const int*   edge  = (const int*)d_in[17];
    const int*   batch = (const int*)d_in[18];

    const int N  = in_sizes[18];        // 100000
    const int E  = in_sizes[17] / 2;    // 1600000
    const int H2 = in_sizes[14];        // 128
    const int Cc = in_sizes[15] / H2;   // 4
    const int G  = out_size / Cc;       // 512

    const int* srcI = edge;
    const int* dstI = edge + E;

    size_t off = 0;
    auto alloc = [&](size_t bytes) {
        char* p = (char*)d_ws + off;
        off = (off + bytes + 255) & ~(size_t)255;
        return p;
    };
    float* h      = (float*)alloc((size_t)N * 256 * 4);
    float* hwp    = (float*)alloc((size_t)N * 256 * 4);
    float* dinv   = (float*)alloc((size_t)N * 4);
    int*   deg    = (int*)alloc((size_t)N * 4);
    int*   rowptr = (int*)alloc((size_t)(N + 1) * 4);
    int*   cursor = (int*)alloc((size_t)N * 4);
    int*   col    = (int*)alloc((size_t)E * 4);
    int*   bsums  = (int*)alloc(1024 * 4);
    int*   starts = (int*)alloc((size_t)(G + 1) * 4);
    float* pooled = (float*)alloc((size_t)G * 256 * 4);
    float* z0     = (float*)alloc((size_t)G * 256 * 4);
    float* z1     = (float*)alloc((size_t)G * H2 * 4);
    unsigned short* Bth[4];
    unsigned short* Btl[4];
    for (int i = 0; i < 4; ++i) {
        Bth[i] = (unsigned short*)alloc((size_t)256 * 256 * 2);
        Btl[i] = (unsigned short*)alloc((size_t)256 * 256 * 2);
    }
    (void)ws_size; (void)n_in;

    hipMemsetAsync(deg, 0, (size_t)N * 4, stream);
    hipMemsetAsync(cursor, 0, (size_t)N * 4, stream);

    // 0. pre-split weights into transposed bf16 hi/lo planes
    const float* Ws[4] = {W_ft, W_g[0], W_g[1], W_g[2]};
    for (int i = 0; i < 4; ++i)
        tg_splitB<<<dim3(4, 4), dim3(256), 0, stream>>>(Ws[i], Bth[i], Btl[i]);

    const int GB = (N + 63) / 64;
    // 1. feature transform: h = relu(x @ W_ft + b_ft)
    tg_gemm_mfma<<<dim3(GB), dim3(256), 0, stream>>>(x, Bth[0], Btl[0], b_ft, nullptr, h, N, 1);
    // 2. LayerNorm + positional encoding (in place)
    tg_ln_pe<<<dim3((N + 3) / 4), dim3(256), 0, stream>>>(h, ln_g, ln_b, N);
    // 3. degrees + CSR build (rows = dst, cols = src)
    tg_count<<<dim3((E + 255) / 256), dim3(256), 0, stream>>>(dstI, deg, E);
    tg_dinv<<<dim3((N + 255) / 256), dim3(256), 0, stream>>>(deg, dinv, N);
    const int NB = (N + 1023) / 1024;
    tg_scan1<<<dim3(NB), dim3(1024), 0, stream>>>(deg, rowptr, bsums, N);
    tg_scan2<<<dim3(1), dim3(1024), 0, stream>>>(bsums, NB);
    tg_scan3<<<dim3((N + 1024) / 1024), dim3(1024), 0, stream>>>(rowptr, bsums, N, E);
    tg_fill<<<dim3((E + 255) / 256), dim3(256), 0, stream>>>(srcI, dstI, rowptr, cursor, col, E);
    // 4. GCN layers
    for (int l = 0; l < 3; ++l) {
        tg_gemm_mfma<<<dim3(GB), dim3(256), 0, stream>>>(h, Bth[l + 1], Btl[l + 1],
                                                         nullptr, dinv, hwp, N, 0);
        tg_aggregate<<<dim3((N + 3) / 4), dim3(256), 0, stream>>>(hwp, rowptr, col, dinv, b_g[l], h, N);
    }
    // 5. per-graph mean pool
    tg_ranges<<<dim3((G + 256) / 256), dim3(256), 0, stream>>>(batch, starts, N, G);
    tg_pool<<<dim3(G), dim3(256), 0, stream>>>(h, starts, pooled, G);
    // 6. classifier MLP
    tg_mlp<<<dim3((G * 256 + 255) / 256), dim3(256), 0, stream>>>(pooled, W_c0, b_c0, z0, G, 256, 256, 1);
    tg_mlp<<<dim3((G * H2 + 255) / 256), dim3(256), 0, stream>>>(z0, W_c1, b_c1, z1, G, 256, H2, 1);
    tg_mlp<<<dim3((G * Cc + 255) / 256), dim3(256), 0, stream>>>(z1, W_c2, b_c2, (float*)d_out, G, H2, Cc, 0);
}

// Round 3
// 1604.318 us; speedup vs baseline: 1.5324x; 1.2837x over previous
//
#include <hip/hip_runtime.h>
#include <math.h>

// ---------------------------------------------------------------------------
// Temporal GNN. Round 3: GEMM restructured — B planes staged via
// global_load_lds (no staging VGPRs), b-frags short-lived => no spills,
// 3 blocks/CU. Aggregate: 2 waves/row (float2) for latency hiding.
// ---------------------------------------------------------------------------

typedef __attribute__((ext_vector_type(8))) short short8;   // 8 bf16 (4 VGPR)
typedef __attribute__((ext_vector_type(4))) float floatx4;  // MFMA C/D

static __device__ __forceinline__ unsigned short f2bf(float f) {
    unsigned u = __float_as_uint(f);
    unsigned r = u + 0x7fff + ((u >> 16) & 1);   // RNE
    return (unsigned short)(r >> 16);
}
static __device__ __forceinline__ float bf2f(unsigned short s) {
    return __uint_as_float(((unsigned)s) << 16);
}

// async 16B/lane global -> LDS (dest = wave-uniform base + lane*16)
static __device__ __forceinline__ void gl_lds16(const void* g, void* l) {
    __builtin_amdgcn_global_load_lds(
        (const __attribute__((address_space(1))) unsigned int*)(g),
        (__attribute__((address_space(3))) unsigned int*)(l), 16, 0, 0);
}

// Split W[256][256] (k-major) into transposed bf16 planes Bt_hi/Bt_lo [n][k].
__global__ void tg_splitB(const float* __restrict__ W,
                          unsigned short* __restrict__ Bth,
                          unsigned short* __restrict__ Btl)
{
    __shared__ float T[64][68];
    const int tk = blockIdx.x * 64, tn = blockIdx.y * 64;
    const int t = threadIdx.x;
#pragma unroll
    for (int j = 0; j < 4; ++j) {
        const int idx = t + 256 * j;
        const int k = idx >> 4, c4 = (idx & 15) * 4;
        const float4 v = *(const float4*)&W[(size_t)(tk + k) * 256 + tn + c4];
        T[k][c4] = v.x; T[k][c4 + 1] = v.y; T[k][c4 + 2] = v.z; T[k][c4 + 3] = v.w;
    }
    __syncthreads();
#pragma unroll
    for (int j = 0; j < 4; ++j) {
        const int idx = t + 256 * j;
        const int n = idx >> 4, q = (idx & 15) * 4;
        unsigned short hh[4], ll[4];
#pragma unroll
        for (int i = 0; i < 4; ++i) {
            const float f = T[q + i][n];
            hh[i] = f2bf(f);
            ll[i] = f2bf(f - bf2f(hh[i]));
        }
        uint2 hp, lp;
        hp.x = (unsigned)hh[0] | ((unsigned)hh[1] << 16);
        hp.y = (unsigned)hh[2] | ((unsigned)hh[3] << 16);
        lp.x = (unsigned)ll[0] | ((unsigned)ll[1] << 16);
        lp.y = (unsigned)ll[2] | ((unsigned)ll[3] << 16);
        *(uint2*)&Bth[(size_t)(tn + n) * 256 + tk + q] = hp;
        *(uint2*)&Btl[(size_t)(tn + n) * 256 + tk + q] = lp;
    }
}

// C[M x 256] = A[M x 256] @ B[256 x 256] via split-bf16 MFMA.
// 256 thr (4 waves), BM=64, BN=256 (wave w owns cols 64w..64w+63), K chunks of 32.
// A: fp32 load -> hi/lo bf16 split -> ds_write ([64][40] padded, 2-way banks).
// B: pre-split bf16 planes [n][k] -> global_load_lds (contiguous [256][32]).
__global__ __launch_bounds__(256, 3)
void tg_gemm_mfma(const float* __restrict__ A,
                  const unsigned short* __restrict__ Bth,
                  const unsigned short* __restrict__ Btl,
                  const float* __restrict__ bias, const float* __restrict__ rowscale,
                  float* __restrict__ C, int M, int do_relu)
{
    __shared__ unsigned short sAh[64][40], sAl[64][40];   // 5 KB each
    __shared__ unsigned short sBh[256 * 32], sBl[256 * 32]; // 16 KB each

    const int t = threadIdx.x;
    const int row0 = blockIdx.x * 64;
    const int w = t >> 6, lane = t & 63;
    const int quad = lane >> 4, l16 = lane & 15;

    floatx4 acc[4][4];
#pragma unroll
    for (int i = 0; i < 4; ++i)
#pragma unroll
        for (int j = 0; j < 4; ++j) acc[i][j] = (floatx4){0.f, 0.f, 0.f, 0.f};

    // A staging: thread t -> row t>>2 (0..63), k offset (t&3)*8
    const int s_ar = t >> 2;
    const int s_ac = (t & 3) * 8;
    const bool arow_ok = (row0 + s_ar) < M;
    const float* Arow = A + (size_t)(row0 + s_ar) * 256 + s_ac;

    // B staging: wave w, instr j covers n rows 64w+16j..+15; lane i -> n=+i/4, k+=(i&3)*8
    const size_t bgoff = (size_t)(64 * w + (lane >> 2)) * 256 + (lane & 3) * 8;

    for (int kc = 0; kc < 8; ++kc) {
        const int k0 = kc * 32;
        __syncthreads();   // previous chunk's fragment reads complete
#pragma unroll
        for (int j = 0; j < 4; ++j) {
            gl_lds16(Bth + bgoff + (size_t)(16 * j) * 256 + k0, &sBh[(64 * w + 16 * j) * 32]);
            gl_lds16(Btl + bgoff + (size_t)(16 * j) * 256 + k0, &sBl[(64 * w + 16 * j) * 32]);
        }
        float4 a0 = make_float4(0.f, 0.f, 0.f, 0.f), a1 = a0;
        if (arow_ok) {
            a0 = *(const float4*)(Arow + k0);
            a1 = *(const float4*)(Arow + k0 + 4);
        }
        const float f[8] = {a0.x, a0.y, a0.z, a0.w, a1.x, a1.y, a1.z, a1.w};
        unsigned short hh[8], ll[8];
#pragma unroll
        for (int i = 0; i < 8; ++i) {
            hh[i] = f2bf(f[i]);
            ll[i] = f2bf(f[i] - bf2f(hh[i]));
        }
        uint4 hp, lp;
        hp.x = (unsigned)hh[0] | ((unsigned)hh[1] << 16);
        hp.y = (unsigned)hh[2] | ((unsigned)hh[3] << 16);
        hp.z = (unsigned)hh[4] | ((unsigned)hh[5] << 16);
        hp.w = (unsigned)hh[6] | ((unsigned)hh[7] << 16);
        lp.x = (unsigned)ll[0] | ((unsigned)ll[1] << 16);
        lp.y = (unsigned)ll[2] | ((unsigned)ll[3] << 16);
        lp.z = (unsigned)ll[4] | ((unsigned)ll[5] << 16);
        lp.w = (unsigned)ll[6] | ((unsigned)ll[7] << 16);
        *(uint4*)&sAh[s_ar][s_ac] = hp;
        *(uint4*)&sAl[s_ar][s_ac] = lp;
        __syncthreads();   // drains vmcnt (global_load_lds) + lgkm (ds_write)

        short8 ah[4], al[4];
#pragma unroll
        for (int rt = 0; rt < 4; ++rt) {
            ah[rt] = *(const short8*)&sAh[rt * 16 + l16][quad * 8];
            al[rt] = *(const short8*)&sAl[rt * 16 + l16][quad * 8];
        }
#pragma unroll
        for (int ct = 0; ct < 4; ++ct) {
            const short8 bh = *(const short8*)&sBh[(w * 64 + ct * 16 + l16) * 32 + quad * 8];
            const short8 bl = *(const short8*)&sBl[(w * 64 + ct * 16 + l16) * 32 + quad * 8];
#pragma unroll
            for (int rt = 0; rt < 4; ++rt) {
                acc[rt][ct] = __builtin_amdgcn_mfma_f32_16x16x32_bf16(ah[rt], bh, acc[rt][ct], 0, 0, 0);
                acc[rt][ct] = __builtin_amdgcn_mfma_f32_16x16x32_bf16(al[rt], bh, acc[rt][ct], 0, 0, 0);
                acc[rt][ct] = __builtin_amdgcn_mfma_f32_16x16x32_bf16(ah[rt], bl, acc[rt][ct], 0, 0, 0);
            }
        }
    }

    // epilogue: row = row0+rt*16+quad*4+i, col = w*64+ct*16+l16
#pragma unroll
    for (int rt = 0; rt < 4; ++rt) {
#pragma unroll
        for (int i = 0; i < 4; ++i) {
            const int gr = row0 + rt * 16 + quad * 4 + i;
            if (gr >= M) continue;
            const float s = rowscale ? rowscale[gr] : 1.f;
#pragma unroll
            for (int ct = 0; ct < 4; ++ct) {
                const int gc = w * 64 + ct * 16 + l16;
                float v = acc[rt][ct][i] * s;
                if (bias) v += bias[gc];
                if (do_relu) v = fmaxf(v, 0.f);
                C[(size_t)gr * 256 + gc] = v;
            }
        }
    }
}

// LayerNorm (in-place) + sinusoidal PE. One wave per row, 4 cols/lane.
__global__ void tg_ln_pe(float* __restrict__ h, const float* __restrict__ g,
                         const float* __restrict__ b, int N)
{
    const int gt = blockIdx.x * blockDim.x + threadIdx.x;
    const int row = gt >> 6;
    const int lane = threadIdx.x & 63;
    if (row >= N) return;
    float* hp = h + (size_t)row * 256 + lane * 4;
    float4 v = *(float4*)hp;
    float s = v.x + v.y + v.z + v.w;
#pragma unroll
    for (int m = 1; m < 64; m <<= 1) s += __shfl_xor(s, m, 64);
    const float mu = s * (1.f / 256.f);
    const float d0 = v.x - mu, d1 = v.y - mu, d2 = v.z - mu, d3 = v.w - mu;
    float q = d0 * d0 + d1 * d1 + d2 * d2 + d3 * d3;
#pragma unroll
    for (int m = 1; m < 64; m <<= 1) q += __shfl_xor(q, m, 64);
    const float rstd = 1.f / sqrtf(q * (1.f / 256.f) + 1e-5f);

    const int c = lane * 4;
    const float4 gg = *(const float4*)&g[c];
    const float4 bb = *(const float4*)&b[c];
    const float cexp = -0.035977892078031970f;  // -log(10000)/256
    const float fn = (float)row;
    const float div0 = expf((float)c * cexp);
    const float div1 = expf((float)(c + 2) * cexp);
    const float a0 = fn * div0;
    const float a1 = fn * div1;
    float4 o;
    o.x = d0 * rstd * gg.x + bb.x + sinf(a0);
    o.y = d1 * rstd * gg.y + bb.y + cosf(a0);
    o.z = d2 * rstd * gg.z + bb.z + sinf(a1);
    o.w = d3 * rstd * gg.w + bb.w + cosf(a1);
    *(float4*)hp = o;
}

__global__ void tg_count(const int* __restrict__ dst, int* __restrict__ deg, int E)
{
    const int e = blockIdx.x * blockDim.x + threadIdx.x;
    if (e < E) atomicAdd(&deg[dst[e]], 1);
}

__global__ void tg_dinv(const int* __restrict__ deg, float* __restrict__ dinv, int N)
{
    const int i = blockIdx.x * blockDim.x + threadIdx.x;
    if (i < N) dinv[i] = 1.f / sqrtf((float)(deg[i] + 1));  // +1 self-loop
}

__global__ void tg_scan1(const int* __restrict__ cnt, int* __restrict__ out,
                         int* __restrict__ sums, int N)
{
    __shared__ int tmp[1024];
    const int t = threadIdx.x;
    const int gid = blockIdx.x * 1024 + t;
    const int v = (gid < N) ? cnt[gid] : 0;
    tmp[t] = v;
    __syncthreads();
    for (int o = 1; o < 1024; o <<= 1) {
        const int add = (t >= o) ? tmp[t - o] : 0;
        __syncthreads();
        tmp[t] += add;
        __syncthreads();
    }
    if (gid < N) out[gid] = tmp[t] - v;
    if (t == 1023) sums[blockIdx.x] = tmp[t];
}

__global__ void tg_scan2(int* __restrict__ sums, int nb)
{
    __shared__ int tmp[1024];
    const int t = threadIdx.x;
    const int v = (t < nb) ? sums[t] : 0;
    tmp[t] = v;
    __syncthreads();
    for (int o = 1; o < 1024; o <<= 1) {
        const int add = (t >= o) ? tmp[t - o] : 0;
        __syncthreads();
        tmp[t] += add;
        __syncthreads();
    }
    if (t < nb) sums[t] = tmp[t] - v;
}

__global__ void tg_scan3(int* __restrict__ rowptr, const int* __restrict__ offs,
                         int N, int E)
{
    const int gid = blockIdx.x * 1024 + threadIdx.x;
    if (gid < N) rowptr[gid] += offs[gid >> 10];
    else if (gid == N) rowptr[N] = E;
}

__global__ void tg_fill(const int* __restrict__ src, const int* __restrict__ dst,
                        const int* __restrict__ rowptr, int* __restrict__ cursor,
                        int* __restrict__ col, int E)
{
    const int e = blockIdx.x * blockDim.x + threadIdx.x;
    if (e >= E) return;
    const int d = dst[e];
    const int p = atomicAdd(&cursor[d], 1);
    col[rowptr[d] + p] = src[e];
}

// out[i] = relu(dinv[i] * (hwp[i] + sum_{src in row i} hwp[src]) + bias)
// TWO waves per row (each owns 128 channels, float2/lane) for latency hiding.
__global__ void tg_aggregate(const float* __restrict__ hwp, const int* __restrict__ rowptr,
                             const int* __restrict__ col, const float* __restrict__ dinv,
                             const float* __restrict__ bias, float* __restrict__ out, int N)
{
    const int gw = (blockIdx.x * blockDim.x + threadIdx.x) >> 6;
    const int row = gw >> 1;
    if (row >= N) return;
    const int half = gw & 1;
    const int lane = threadIdx.x & 63;
    const int c = half * 128 + lane * 2;
    const float* base = hwp + c;
    float2 acc = *(const float2*)(base + (size_t)row * 256);
    const int beg = rowptr[row], end = rowptr[row + 1];
    int p = beg;
    for (; p + 4 <= end; p += 4) {
        const int j0 = col[p], j1 = col[p + 1], j2 = col[p + 2], j3 = col[p + 3];
        const float2 v0 = *(const float2*)(base + (size_t)j0 * 256);
        const float2 v1 = *(const float2*)(base + (size_t)j1 * 256);
        const float2 v2 = *(const float2*)(base + (size_t)j2 * 256);
        const float2 v3 = *(const float2*)(base + (size_t)j3 * 256);
        acc.x += v0.x + v1.x + v2.x + v3.x;
        acc.y += v0.y + v1.y + v2.y + v3.y;
    }
    for (; p < end; ++p) {
        const int j = col[p];
        const float2 v = *(const float2*)(base + (size_t)j * 256);
        acc.x += v.x; acc.y += v.y;
    }
    const float di = dinv[row];
    const float2 bb = *(const float2*)&bias[c];
    float2 o;
    o.x = fmaxf(di * acc.x + bb.x, 0.f);
    o.y = fmaxf(di * acc.y + bb.y, 0.f);
    *(float2*)&out[(size_t)row * 256 + c] = o;
}

__global__ void tg_ranges(const int* __restrict__ batch, int* __restrict__ starts,
                          int N, int G)
{
    const int g = blockIdx.x * blockDim.x + threadIdx.x;
    if (g > G) return;
    int lo = 0, hi = N;
    while (lo < hi) {
        const int mid = (lo + hi) >> 1;
        if (batch[mid] < g) lo = mid + 1; else hi = mid;
    }
    starts[g] = lo;
}

__global__ void tg_pool(const float* __restrict__ h, const int* __restrict__ starts,
                        float* __restrict__ pooled, int G)
{
    const int g = blockIdx.x;
    const int c = threadIdx.x;
    const int beg = starts[g], end = starts[g + 1];
    float s = 0.f;
    for (int r = beg; r < end; ++r) s += h[(size_t)r * 256 + c];
    const float cnt = (float)(end - beg);
    pooled[(size_t)g * 256 + c] = s / fmaxf(cnt, 1.f);
}

__global__ void tg_mlp(const float* __restrict__ A, const float* __restrict__ B,
                       const float* __restrict__ bias, float* __restrict__ Cout,
                       int M, int K, int Nc, int do_relu)
{
    const int idx = blockIdx.x * blockDim.x + threadIdx.x;
    if (idx >= M * Nc) return;
    const int m = idx / Nc;
    const int n = idx - m * Nc;
    float acc = 0.f;
    for (int k = 0; k < K; ++k) acc += A[(size_t)m * K + k] * B[(size_t)k * Nc + n];
    acc += bias[n];
    Cout[idx] = do_relu ? fmaxf(acc, 0.f) : acc;
}

extern "C" void kernel_launch(void* const* d_in, const int* in_sizes, int n_in,
                              void* d_out, int out_size, void* d_ws, size_t ws_size,
                              hipStream_t stream)
{
    const float* x    = (const float*)d_in[0];
    const float* W_ft = (const float*)d_in[1];
    const float* b_ft = (const float*)d_in[2];
    const float* ln_g = (const float*)d_in[3];
    const float* ln_b = (const float*)d_in[4];
    const float* W_g[3] = {(const float*)d_in[5], (const float*)d_in[7], (const float*)d_in[9]};
    const float* b_g[3] = {(const float*)d_in[6], (const float*)d_in[8], (const float*)d_in[10]};
    const float* W_c0 = (const float*)d_in[11];
    const float* b_c0 = (const float*)d_in[12];
    const float* W_c1 = (const float*)d_in[13];
    const float* b_c1 = (const float*)d_in[14];
    const float* W_c2 = (const float*)d_in[15];
    const float* b_c2 = (const float*)d_in[16];
    const int*   edge  = (const int*)d_in[17];
    const int*   batch = (const int*)d_in[18];

    const int N  = in_sizes[18];        // 100000
    const int E  = in_sizes[17] / 2;    // 1600000
    const int H2 = in_sizes[14];        // 128
    const int Cc = in_sizes[15] / H2;   // 4
    const int G  = out_size / Cc;       // 512

    const int* srcI = edge;
    const int* dstI = edge + E;

    size_t off = 0;
    auto alloc = [&](size_t bytes) {
        char* p = (char*)d_ws + off;
        off = (off + bytes + 255) & ~(size_t)255;
        return p;
    };
    float* h      = (float*)alloc((size_t)N * 256 * 4);
    float* hwp    = (float*)alloc((size_t)N * 256 * 4);
    float* dinv   = (float*)alloc((size_t)N * 4);
    int*   deg    = (int*)alloc((size_t)N * 4);
    int*   rowptr = (int*)alloc((size_t)(N + 1) * 4);
    int*   cursor = (int*)alloc((size_t)N * 4);
    int*   col    = (int*)alloc((size_t)E * 4);
    int*   bsums  = (int*)alloc(1024 * 4);
    int*   starts = (int*)alloc((size_t)(G + 1) * 4);
    float* pooled = (float*)alloc((size_t)G * 256 * 4);
    float* z0     = (float*)alloc((size_t)G * 256 * 4);
    float* z1     = (float*)alloc((size_t)G * H2 * 4);
    unsigned short* Bth[4];
    unsigned short* Btl[4];
    for (int i = 0; i < 4; ++i) {
        Bth[i] = (unsigned short*)alloc((size_t)256 * 256 * 2);
        Btl[i] = (unsigned short*)alloc((size_t)256 * 256 * 2);
    }
    (void)ws_size; (void)n_in;

    hipMemsetAsync(deg, 0, (size_t)N * 4, stream);
    hipMemsetAsync(cursor, 0, (size_t)N * 4, stream);

    // 0. pre-split weights into transposed bf16 hi/lo planes
    const float* Ws[4] = {W_ft, W_g[0], W_g[1], W_g[2]};
    for (int i = 0; i < 4; ++i)
        tg_splitB<<<dim3(4, 4), dim3(256), 0, stream>>>(Ws[i], Bth[i], Btl[i]);

    const int GB = (N + 63) / 64;
    // 1. feature transform: h = relu(x @ W_ft + b_ft)
    tg_gemm_mfma<<<dim3(GB), dim3(256), 0, stream>>>(x, Bth[0], Btl[0], b_ft, nullptr, h, N, 1);
    // 2. LayerNorm + positional encoding (in place)
    tg_ln_pe<<<dim3((N + 3) / 4), dim3(256), 0, stream>>>(h, ln_g, ln_b, N);
    // 3. degrees + CSR build (rows = dst, cols = src)
    tg_count<<<dim3((E + 255) / 256), dim3(256), 0, stream>>>(dstI, deg, E);
    tg_dinv<<<dim3((N + 255) / 256), dim3(256), 0, stream>>>(deg, dinv, N);
    const int NB = (N + 1023) / 1024;
    tg_scan1<<<dim3(NB), dim3(1024), 0, stream>>>(deg, rowptr, bsums, N);
    tg_scan2<<<dim3(1), dim3(1024), 0, stream>>>(bsums, NB);
    tg_scan3<<<dim3((N + 1024) / 1024), dim3(1024), 0, stream>>>(rowptr, bsums, N, E);
    tg_fill<<<dim3((E + 255) / 256), dim3(256), 0, stream>>>(srcI, dstI, rowptr, cursor, col, E);
    // 4. GCN layers
    for (int l = 0; l < 3; ++l) {
        tg_gemm_mfma<<<dim3(GB), dim3(256), 0, stream>>>(h, Bth[l + 1], Btl[l + 1],
                                                         nullptr, dinv, hwp, N, 0);
        tg_aggregate<<<dim3((N + 1) / 2), dim3(256), 0, stream>>>(hwp, rowptr, col, dinv, b_g[l], h, N);
    }
    // 5. per-graph mean pool
    tg_ranges<<<dim3((G + 256) / 256), dim3(256), 0, stream>>>(batch, starts, N, G);
    tg_pool<<<dim3(G), dim3(256), 0, stream>>>(h, starts, pooled, G);
    // 6. classifier MLP
    tg_mlp<<<dim3((G * 256 + 255) / 256), dim3(256), 0, stream>>>(pooled, W_c0, b_c0, z0, G, 256, 256, 1);
    tg_mlp<<<dim3((G * H2 + 255) / 256), dim3(256), 0, stream>>>(z0, W_c1, b_c1, z1, G, 256, H2, 1);
    tg_mlp<<<dim3((G * Cc + 255) / 256), dim3(256), 0, stream>>>(z1, W_c2, b_c2, (float*)d_out, G, H2, Cc, 0);
}

// Round 4
// 1249.461 us; speedup vs baseline: 1.9677x; 1.2840x over previous
//
#include <hip/hip_runtime.h>
#include <math.h>

// ---------------------------------------------------------------------------
// Temporal GNN. Round 4:
//  * hwp stored bf16 -> aggregate gather traffic halved
//  * h carried as split bf16 hi/lo planes -> GCN GEMM A staged via
//    global_load_lds (no VALU split in K-loop)
//  * XOR-swizzled LDS (slot = r*4 + (kg ^ ((r+(r>>2))&3))) -> conflict-free
//    ds_read_b128 / ds_write_b128 (was 8-way)
// ---------------------------------------------------------------------------

typedef __attribute__((ext_vector_type(8))) short short8;   // 8 bf16
typedef __attribute__((ext_vector_type(4))) float floatx4;  // MFMA C/D

#define SWZ(r) (((r) + ((r) >> 2)) & 3)

static __device__ __forceinline__ unsigned short f2bf(float f) {
    unsigned u = __float_as_uint(f);
    unsigned r = u + 0x7fff + ((u >> 16) & 1);   // RNE
    return (unsigned short)(r >> 16);
}
static __device__ __forceinline__ float bf2f(unsigned short s) {
    return __uint_as_float(((unsigned)s) << 16);
}

// async 16B/lane global -> LDS (dest = wave-uniform base + lane*16)
static __device__ __forceinline__ void gl_lds16(const void* g, void* l) {
    __builtin_amdgcn_global_load_lds(
        (const __attribute__((address_space(1))) unsigned int*)(g),
        (__attribute__((address_space(3))) unsigned int*)(l), 16, 0, 0);
}

// Split W[256][256] (k-major) into transposed bf16 planes Bt_hi/Bt_lo [n][k].
__global__ void tg_splitB(const float* __restrict__ W,
                          unsigned short* __restrict__ Bth,
                          unsigned short* __restrict__ Btl)
{
    __shared__ float T[64][68];
    const int tk = blockIdx.x * 64, tn = blockIdx.y * 64;
    const int t = threadIdx.x;
#pragma unroll
    for (int j = 0; j < 4; ++j) {
        const int idx = t + 256 * j;
        const int k = idx >> 4, c4 = (idx & 15) * 4;
        const float4 v = *(const float4*)&W[(size_t)(tk + k) * 256 + tn + c4];
        T[k][c4] = v.x; T[k][c4 + 1] = v.y; T[k][c4 + 2] = v.z; T[k][c4 + 3] = v.w;
    }
    __syncthreads();
#pragma unroll
    for (int j = 0; j < 4; ++j) {
        const int idx = t + 256 * j;
        const int n = idx >> 4, q = (idx & 15) * 4;
        unsigned short hh[4], ll[4];
#pragma unroll
        for (int i = 0; i < 4; ++i) {
            const float f = T[q + i][n];
            hh[i] = f2bf(f);
            ll[i] = f2bf(f - bf2f(hh[i]));
        }
        uint2 hp, lp;
        hp.x = (unsigned)hh[0] | ((unsigned)hh[1] << 16);
        hp.y = (unsigned)hh[2] | ((unsigned)hh[3] << 16);
        lp.x = (unsigned)ll[0] | ((unsigned)ll[1] << 16);
        lp.y = (unsigned)ll[2] | ((unsigned)ll[3] << 16);
        *(uint2*)&Bth[(size_t)(tn + n) * 256 + tk + q] = hp;
        *(uint2*)&Btl[(size_t)(tn + n) * 256 + tk + q] = lp;
    }
}

// ---- FT GEMM: A fp32 (x), on-the-fly split, out = relu(A@B + bias) as hi/lo
__global__ __launch_bounds__(256, 3)
void tg_gemm_ft(const float* __restrict__ A,
                const unsigned short* __restrict__ Bth,
                const unsigned short* __restrict__ Btl,
                const float* __restrict__ bias,
                unsigned short* __restrict__ outHi,
                unsigned short* __restrict__ outLo, int M)
{
    __shared__ unsigned short sAh[64 * 32], sAl[64 * 32];   // 4 KB each
    __shared__ unsigned short sBh[256 * 32], sBl[256 * 32]; // 16 KB each

    const int t = threadIdx.x;
    const int row0 = blockIdx.x * 64;
    const int w = t >> 6, lane = t & 63;
    const int quad = lane >> 4, l16 = lane & 15;

    floatx4 acc[4][4];
#pragma unroll
    for (int i = 0; i < 4; ++i)
#pragma unroll
        for (int j = 0; j < 4; ++j) acc[i][j] = (floatx4){0.f, 0.f, 0.f, 0.f};

    const int s_ar = t >> 2;                       // 0..63
    const int s_kg = t & 3;
    const int s_slot = s_ar * 4 + (s_kg ^ SWZ(s_ar & 15));
    const bool arow_ok = (row0 + s_ar) < M;
    const float* Arow = A + (size_t)(row0 + s_ar) * 256 + s_kg * 8;

    const int b_kgs = (lane & 3) ^ SWZ(lane >> 2); // swizzled source k-group
    const size_t bsrc = (size_t)(64 * w + (lane >> 2)) * 256 + b_kgs * 8;

    const int r_swz = SWZ(l16);

    for (int kc = 0; kc < 8; ++kc) {
        const int k0 = kc * 32;
        __syncthreads();
#pragma unroll
        for (int j = 0; j < 4; ++j) {
            gl_lds16(Bth + bsrc + (size_t)(16 * j) * 256 + k0, &sBh[(64 * w + 16 * j) * 32]);
            gl_lds16(Btl + bsrc + (size_t)(16 * j) * 256 + k0, &sBl[(64 * w + 16 * j) * 32]);
        }
        float4 a0 = make_float4(0.f, 0.f, 0.f, 0.f), a1 = a0;
        if (arow_ok) {
            a0 = *(const float4*)(Arow + k0);
            a1 = *(const float4*)(Arow + k0 + 4);
        }
        const float f[8] = {a0.x, a0.y, a0.z, a0.w, a1.x, a1.y, a1.z, a1.w};
        unsigned short hh[8], ll[8];
#pragma unroll
        for (int i = 0; i < 8; ++i) {
            hh[i] = f2bf(f[i]);
            ll[i] = f2bf(f[i] - bf2f(hh[i]));
        }
        uint4 hp, lp;
        hp.x = (unsigned)hh[0] | ((unsigned)hh[1] << 16);
        hp.y = (unsigned)hh[2] | ((unsigned)hh[3] << 16);
        hp.z = (unsigned)hh[4] | ((unsigned)hh[5] << 16);
        hp.w = (unsigned)hh[6] | ((unsigned)hh[7] << 16);
        lp.x = (unsigned)ll[0] | ((unsigned)ll[1] << 16);
        lp.y = (unsigned)ll[2] | ((unsigned)ll[3] << 16);
        lp.z = (unsigned)ll[4] | ((unsigned)ll[5] << 16);
        lp.w = (unsigned)ll[6] | ((unsigned)ll[7] << 16);
        *(uint4*)&sAh[s_slot * 8] = hp;
        *(uint4*)&sAl[s_slot * 8] = lp;
        __syncthreads();

        short8 ah[4], al[4];
#pragma unroll
        for (int rt = 0; rt < 4; ++rt) {
            const int sl = (rt * 16 + l16) * 4 + (quad ^ r_swz);
            ah[rt] = *(const short8*)&sAh[sl * 8];
            al[rt] = *(const short8*)&sAl[sl * 8];
        }
#pragma unroll
        for (int ct = 0; ct < 4; ++ct) {
            const int sl = (64 * w + ct * 16 + l16) * 4 + (quad ^ r_swz);
            const short8 bh = *(const short8*)&sBh[sl * 8];
            const short8 bl = *(const short8*)&sBl[sl * 8];
#pragma unroll
            for (int rt = 0; rt < 4; ++rt) {
                acc[rt][ct] = __builtin_amdgcn_mfma_f32_16x16x32_bf16(ah[rt], bh, acc[rt][ct], 0, 0, 0);
                acc[rt][ct] = __builtin_amdgcn_mfma_f32_16x16x32_bf16(al[rt], bh, acc[rt][ct], 0, 0, 0);
                acc[rt][ct] = __builtin_amdgcn_mfma_f32_16x16x32_bf16(ah[rt], bl, acc[rt][ct], 0, 0, 0);
            }
        }
    }

#pragma unroll
    for (int rt = 0; rt < 4; ++rt) {
#pragma unroll
        for (int i = 0; i < 4; ++i) {
            const int gr = row0 + rt * 16 + quad * 4 + i;
            if (gr >= M) continue;
#pragma unroll
            for (int ct = 0; ct < 4; ++ct) {
                const int gc = w * 64 + ct * 16 + l16;
                float v = acc[rt][ct][i] + bias[gc];
                v = fmaxf(v, 0.f);
                const unsigned short hi = f2bf(v);
                const unsigned short lo = f2bf(v - bf2f(hi));
                outHi[(size_t)gr * 256 + gc] = hi;
                outLo[(size_t)gr * 256 + gc] = lo;
            }
        }
    }
}

// ---- GCN GEMM: A = pre-split hi/lo planes (rows multiple of 64), out = bf16
__global__ __launch_bounds__(256, 3)
void tg_gemm_gcn(const unsigned short* __restrict__ Ahp,
                 const unsigned short* __restrict__ Alp,
                 const unsigned short* __restrict__ Bth,
                 const unsigned short* __restrict__ Btl,
                 const float* __restrict__ rowscale,
                 unsigned short* __restrict__ outBf)
{
    __shared__ unsigned short sAh[64 * 32], sAl[64 * 32];
    __shared__ unsigned short sBh[256 * 32], sBl[256 * 32];

    const int t = threadIdx.x;
    const int row0 = blockIdx.x * 64;
    const int w = t >> 6, lane = t & 63;
    const int quad = lane >> 4, l16 = lane & 15;

    floatx4 acc[4][4];
#pragma unroll
    for (int i = 0; i < 4; ++i)
#pragma unroll
        for (int j = 0; j < 4; ++j) acc[i][j] = (floatx4){0.f, 0.f, 0.f, 0.f};

    const int kgs = (lane & 3) ^ SWZ(lane >> 2);
    const size_t asrc = (size_t)(row0 + 16 * w + (lane >> 2)) * 256 + kgs * 8;
    const size_t bsrc = (size_t)(64 * w + (lane >> 2)) * 256 + kgs * 8;
    const int r_swz = SWZ(l16);

    for (int kc = 0; kc < 8; ++kc) {
        const int k0 = kc * 32;
        __syncthreads();
        gl_lds16(Ahp + asrc + k0, &sAh[(16 * w) * 32]);
        gl_lds16(Alp + asrc + k0, &sAl[(16 * w) * 32]);
#pragma unroll
        for (int j = 0; j < 4; ++j) {
            gl_lds16(Bth + bsrc + (size_t)(16 * j) * 256 + k0, &sBh[(64 * w + 16 * j) * 32]);
            gl_lds16(Btl + bsrc + (size_t)(16 * j) * 256 + k0, &sBl[(64 * w + 16 * j) * 32]);
        }
        __syncthreads();

        short8 ah[4], al[4];
#pragma unroll
        for (int rt = 0; rt < 4; ++rt) {
            const int sl = (rt * 16 + l16) * 4 + (quad ^ r_swz);
            ah[rt] = *(const short8*)&sAh[sl * 8];
            al[rt] = *(const short8*)&sAl[sl * 8];
        }
#pragma unroll
        for (int ct = 0; ct < 4; ++ct) {
            const int sl = (64 * w + ct * 16 + l16) * 4 + (quad ^ r_swz);
            const short8 bh = *(const short8*)&sBh[sl * 8];
            const short8 bl = *(const short8*)&sBl[sl * 8];
#pragma unroll
            for (int rt = 0; rt < 4; ++rt) {
                acc[rt][ct] = __builtin_amdgcn_mfma_f32_16x16x32_bf16(ah[rt], bh, acc[rt][ct], 0, 0, 0);
                acc[rt][ct] = __builtin_amdgcn_mfma_f32_16x16x32_bf16(al[rt], bh, acc[rt][ct], 0, 0, 0);
                acc[rt][ct] = __builtin_amdgcn_mfma_f32_16x16x32_bf16(ah[rt], bl, acc[rt][ct], 0, 0, 0);
            }
        }
    }

#pragma unroll
    for (int rt = 0; rt < 4; ++rt) {
#pragma unroll
        for (int i = 0; i < 4; ++i) {
            const int gr = row0 + rt * 16 + quad * 4 + i;
            const float s = rowscale[gr];
#pragma unroll
            for (int ct = 0; ct < 4; ++ct) {
                const int gc = w * 64 + ct * 16 + l16;
                outBf[(size_t)gr * 256 + gc] = f2bf(acc[rt][ct][i] * s);
            }
        }
    }
}

// LayerNorm + PE over split hi/lo planes (in place). One wave per row.
__global__ void tg_ln_pe(unsigned short* __restrict__ hh, unsigned short* __restrict__ hl,
                         const float* __restrict__ g, const float* __restrict__ b, int N)
{
    const int gt = blockIdx.x * blockDim.x + threadIdx.x;
    const int row = gt >> 6;
    const int lane = threadIdx.x & 63;
    if (row >= N) return;
    const int c = lane * 4;
    unsigned short* hp = hh + (size_t)row * 256 + c;
    unsigned short* lp = hl + (size_t)row * 256 + c;
    const ushort4 vh = *(const ushort4*)hp;
    const ushort4 vl = *(const ushort4*)lp;
    const float v0 = bf2f(vh.x) + bf2f(vl.x);
    const float v1 = bf2f(vh.y) + bf2f(vl.y);
    const float v2 = bf2f(vh.z) + bf2f(vl.z);
    const float v3 = bf2f(vh.w) + bf2f(vl.w);
    float s = v0 + v1 + v2 + v3;
#pragma unroll
    for (int m = 1; m < 64; m <<= 1) s += __shfl_xor(s, m, 64);
    const float mu = s * (1.f / 256.f);
    const float d0 = v0 - mu, d1 = v1 - mu, d2 = v2 - mu, d3 = v3 - mu;
    float q = d0 * d0 + d1 * d1 + d2 * d2 + d3 * d3;
#pragma unroll
    for (int m = 1; m < 64; m <<= 1) q += __shfl_xor(q, m, 64);
    const float rstd = 1.f / sqrtf(q * (1.f / 256.f) + 1e-5f);

    const float4 gg = *(const float4*)&g[c];
    const float4 bb = *(const float4*)&b[c];
    const float cexp = -0.035977892078031970f;  // -log(10000)/256
    const float fn = (float)row;
    const float div0 = expf((float)c * cexp);
    const float div1 = expf((float)(c + 2) * cexp);
    const float a0 = fn * div0;
    const float a1 = fn * div1;
    float o[4];
    o[0] = d0 * rstd * gg.x + bb.x + sinf(a0);
    o[1] = d1 * rstd * gg.y + bb.y + cosf(a0);
    o[2] = d2 * rstd * gg.z + bb.z + sinf(a1);
    o[3] = d3 * rstd * gg.w + bb.w + cosf(a1);
    ushort4 oh, ol;
    oh.x = f2bf(o[0]); ol.x = f2bf(o[0] - bf2f(oh.x));
    oh.y = f2bf(o[1]); ol.y = f2bf(o[1] - bf2f(oh.y));
    oh.z = f2bf(o[2]); ol.z = f2bf(o[2] - bf2f(oh.z));
    oh.w = f2bf(o[3]); ol.w = f2bf(o[3] - bf2f(oh.w));
    *(ushort4*)hp = oh;
    *(ushort4*)lp = ol;
}

__global__ void tg_count(const int* __restrict__ dst, int* __restrict__ deg, int E)
{
    const int e = blockIdx.x * blockDim.x + threadIdx.x;
    if (e < E) atomicAdd(&deg[dst[e]], 1);
}

__global__ void tg_dinv(const int* __restrict__ deg, float* __restrict__ dinv, int N)
{
    const int i = blockIdx.x * blockDim.x + threadIdx.x;
    if (i < N) dinv[i] = 1.f / sqrtf((float)(deg[i] + 1));  // +1 self-loop
}

__global__ void tg_scan1(const int* __restrict__ cnt, int* __restrict__ out,
                         int* __restrict__ sums, int N)
{
    __shared__ int tmp[1024];
    const int t = threadIdx.x;
    const int gid = blockIdx.x * 1024 + t;
    const int v = (gid < N) ? cnt[gid] : 0;
    tmp[t] = v;
    __syncthreads();
    for (int o = 1; o < 1024; o <<= 1) {
        const int add = (t >= o) ? tmp[t - o] : 0;
        __syncthreads();
        tmp[t] += add;
        __syncthreads();
    }
    if (gid < N) out[gid] = tmp[t] - v;
    if (t == 1023) sums[blockIdx.x] = tmp[t];
}

__global__ void tg_scan2(int* __restrict__ sums, int nb)
{
    __shared__ int tmp[1024];
    const int t = threadIdx.x;
    const int v = (t < nb) ? sums[t] : 0;
    tmp[t] = v;
    __syncthreads();
    for (int o = 1; o < 1024; o <<= 1) {
        const int add = (t >= o) ? tmp[t - o] : 0;
        __syncthreads();
        tmp[t] += add;
        __syncthreads();
    }
    if (t < nb) sums[t] = tmp[t] - v;
}

__global__ void tg_scan3(int* __restrict__ rowptr, const int* __restrict__ offs,
                         int N, int E)
{
    const int gid = blockIdx.x * 1024 + threadIdx.x;
    if (gid < N) rowptr[gid] += offs[gid >> 10];
    else if (gid == N) rowptr[N] = E;
}

__global__ void tg_fill(const int* __restrict__ src, const int* __restrict__ dst,
                        const int* __restrict__ rowptr, int* __restrict__ cursor,
                        int* __restrict__ col, int E)
{
    const int e = blockIdx.x * blockDim.x + threadIdx.x;
    if (e >= E) return;
    const int d = dst[e];
    const int p = atomicAdd(&cursor[d], 1);
    col[rowptr[d] + p] = src[e];
}

// out = relu(dinv[i]*(hwp[i] + sum hwp[src]) + bias), hwp bf16, out split hi/lo.
// One wave per row, 4 channels/lane (ushort4 = 8B gather per neighbor).
__global__ void tg_aggregate_bf(const unsigned short* __restrict__ hwpb,
                                const int* __restrict__ rowptr, const int* __restrict__ col,
                                const float* __restrict__ dinv, const float* __restrict__ bias,
                                unsigned short* __restrict__ hh, unsigned short* __restrict__ hl,
                                int N)
{
    const int row = (blockIdx.x * blockDim.x + threadIdx.x) >> 6;
    if (row >= N) return;
    const int lane = threadIdx.x & 63;
    const int c = lane * 4;
    const unsigned short* base = hwpb + c;
    const ushort4 sv = *(const ushort4*)(base + (size_t)row * 256);
    float a0 = bf2f(sv.x), a1 = bf2f(sv.y), a2 = bf2f(sv.z), a3 = bf2f(sv.w);
    const int beg = rowptr[row], end = rowptr[row + 1];
    int p = beg;
    for (; p + 4 <= end; p += 4) {
        const int j0 = col[p], j1 = col[p + 1], j2 = col[p + 2], j3 = col[p + 3];
        const ushort4 v0 = *(const ushort4*)(base + (size_t)j0 * 256);
        const ushort4 v1 = *(const ushort4*)(base + (size_t)j1 * 256);
        const ushort4 v2 = *(const ushort4*)(base + (size_t)j2 * 256);
        const ushort4 v3 = *(const ushort4*)(base + (size_t)j3 * 256);
        a0 += bf2f(v0.x) + bf2f(v1.x) + bf2f(v2.x) + bf2f(v3.x);
        a1 += bf2f(v0.y) + bf2f(v1.y) + bf2f(v2.y) + bf2f(v3.y);
        a2 += bf2f(v0.z) + bf2f(v1.z) + bf2f(v2.z) + bf2f(v3.z);
        a3 += bf2f(v0.w) + bf2f(v1.w) + bf2f(v2.w) + bf2f(v3.w);
    }
    for (; p < end; ++p) {
        const ushort4 v = *(const ushort4*)(base + (size_t)col[p] * 256);
        a0 += bf2f(v.x); a1 += bf2f(v.y); a2 += bf2f(v.z); a3 += bf2f(v.w);
    }
    const float di = dinv[row];
    const float4 bb = *(const float4*)&bias[c];
    float o[4];
    o[0] = fmaxf(di * a0 + bb.x, 0.f);
    o[1] = fmaxf(di * a1 + bb.y, 0.f);
    o[2] = fmaxf(di * a2 + bb.z, 0.f);
    o[3] = fmaxf(di * a3 + bb.w, 0.f);
    ushort4 oh, ol;
    oh.x = f2bf(o[0]); ol.x = f2bf(o[0] - bf2f(oh.x));
    oh.y = f2bf(o[1]); ol.y = f2bf(o[1] - bf2f(oh.y));
    oh.z = f2bf(o[2]); ol.z = f2bf(o[2] - bf2f(oh.z));
    oh.w = f2bf(o[3]); ol.w = f2bf(o[3] - bf2f(oh.w));
    *(ushort4*)&hh[(size_t)row * 256 + c] = oh;
    *(ushort4*)&hl[(size_t)row * 256 + c] = ol;
}

__global__ void tg_ranges(const int* __restrict__ batch, int* __restrict__ starts,
                          int N, int G)
{
    const int g = blockIdx.x * blockDim.x + threadIdx.x;
    if (g > G) return;
    int lo = 0, hi = N;
    while (lo < hi) {
        const int mid = (lo + hi) >> 1;
        if (batch[mid] < g) lo = mid + 1; else hi = mid;
    }
    starts[g] = lo;
}

__global__ void tg_pool(const unsigned short* __restrict__ hh,
                        const unsigned short* __restrict__ hl,
                        const int* __restrict__ starts, float* __restrict__ pooled, int G)
{
    const int g = blockIdx.x;
    const int c = threadIdx.x;
    const int beg = starts[g], end = starts[g + 1];
    float s = 0.f;
    for (int r = beg; r < end; ++r)
        s += bf2f(hh[(size_t)r * 256 + c]) + bf2f(hl[(size_t)r * 256 + c]);
    const float cnt = (float)(end - beg);
    pooled[(size_t)g * 256 + c] = s / fmaxf(cnt, 1.f);
}

__global__ void tg_mlp(const float* __restrict__ A, const float* __restrict__ B,
                       const float* __restrict__ bias, float* __restrict__ Cout,
                       int M, int K, int Nc, int do_relu)
{
    const int idx = blockIdx.x * blockDim.x + threadIdx.x;
    if (idx >= M * Nc) return;
    const int m = idx / Nc;
    const int n = idx - m * Nc;
    float acc = 0.f;
    for (int k = 0; k < K; ++k) acc += A[(size_t)m * K + k] * B[(size_t)k * Nc + n];
    acc += bias[n];
    Cout[idx] = do_relu ? fmaxf(acc, 0.f) : acc;
}

extern "C" void kernel_launch(void* const* d_in, const int* in_sizes, int n_in,
                              void* d_out, int out_size, void* d_ws, size_t ws_size,
                              hipStream_t stream)
{
    const float* x    = (const float*)d_in[0];
    const float* W_ft = (const float*)d_in[1];
    const float* b_ft = (const float*)d_in[2];
    const float* ln_g = (const float*)d_in[3];
    const float* ln_b = (const float*)d_in[4];
    const float* W_g[3] = {(const float*)d_in[5], (const float*)d_in[7], (const float*)d_in[9]};
    const float* b_g[3] = {(const float*)d_in[6], (const float*)d_in[8], (const float*)d_in[10]};
    const float* W_c0 = (const float*)d_in[11];
    const float* b_c0 = (const float*)d_in[12];
    const float* W_c1 = (const float*)d_in[13];
    const float* b_c1 = (const float*)d_in[14];
    const float* W_c2 = (const float*)d_in[15];
    const float* b_c2 = (const float*)d_in[16];
    const int*   edge  = (const int*)d_in[17];
    const int*   batch = (const int*)d_in[18];

    const int N    = in_sizes[18];        // 100000
    const int E    = in_sizes[17] / 2;    // 1600000
    const int Mpad = (N + 63) & ~63;      // 100032
    const int H2   = in_sizes[14];        // 128
    const int Cc   = in_sizes[15] / H2;   // 4
    const int G    = out_size / Cc;       // 512

    const int* srcI = edge;
    const int* dstI = edge + E;

    size_t off = 0;
    auto alloc = [&](size_t bytes) {
        char* p = (char*)d_ws + off;
        off = (off + bytes + 255) & ~(size_t)255;
        return p;
    };
    unsigned short* hh   = (unsigned short*)alloc((size_t)Mpad * 256 * 2);
    unsigned short* hl   = (unsigned short*)alloc((size_t)Mpad * 256 * 2);
    unsigned short* hwpb = (unsigned short*)alloc((size_t)Mpad * 256 * 2);
    float* dinv   = (float*)alloc((size_t)Mpad * 4);
    int*   deg    = (int*)alloc((size_t)Mpad * 4);
    int*   rowptr = (int*)alloc((size_t)(N + 1) * 4);
    int*   cursor = (int*)alloc((size_t)N * 4);
    int*   col    = (int*)alloc((size_t)E * 4);
    int*   bsums  = (int*)alloc(1024 * 4);
    int*   starts = (int*)alloc((size_t)(G + 1) * 4);
    float* pooled = (float*)alloc((size_t)G * 256 * 4);
    float* z0     = (float*)alloc((size_t)G * 256 * 4);
    float* z1     = (float*)alloc((size_t)G * H2 * 4);
    unsigned short* Bth[4];
    unsigned short* Btl[4];
    for (int i = 0; i < 4; ++i) {
        Bth[i] = (unsigned short*)alloc((size_t)256 * 256 * 2);
        Btl[i] = (unsigned short*)alloc((size_t)256 * 256 * 2);
    }
    (void)ws_size; (void)n_in;

    hipMemsetAsync(deg, 0, (size_t)Mpad * 4, stream);
    hipMemsetAsync(cursor, 0, (size_t)N * 4, stream);
    // zero the pad rows of the h planes (read by GCN GEMM A staging)
    hipMemsetAsync(hh + (size_t)N * 256, 0, (size_t)(Mpad - N) * 256 * 2, stream);
    hipMemsetAsync(hl + (size_t)N * 256, 0, (size_t)(Mpad - N) * 256 * 2, stream);

    // 0. pre-split weights into transposed bf16 hi/lo planes
    const float* Ws[4] = {W_ft, W_g[0], W_g[1], W_g[2]};
    for (int i = 0; i < 4; ++i)
        tg_splitB<<<dim3(4, 4), dim3(256), 0, stream>>>(Ws[i], Bth[i], Btl[i]);

    const int GB = Mpad / 64;
    // 1. feature transform -> h split planes
    tg_gemm_ft<<<dim3(GB), dim3(256), 0, stream>>>(x, Bth[0], Btl[0], b_ft, hh, hl, N);
    // 2. LayerNorm + positional encoding (in place on planes)
    tg_ln_pe<<<dim3((N + 3) / 4), dim3(256), 0, stream>>>(hh, hl, ln_g, ln_b, N);
    // 3. degrees + CSR build (rows = dst, cols = src)
    tg_count<<<dim3((E + 255) / 256), dim3(256), 0, stream>>>(dstI, deg, E);
    tg_dinv<<<dim3((Mpad + 255) / 256), dim3(256), 0, stream>>>(deg, dinv, Mpad);
    const int NB = (N + 1023) / 1024;
    tg_scan1<<<dim3(NB), dim3(1024), 0, stream>>>(deg, rowptr, bsums, N);
    tg_scan2<<<dim3(1), dim3(1024), 0, stream>>>(bsums, NB);
    tg_scan3<<<dim3((N + 1024) / 1024), dim3(1024), 0, stream>>>(rowptr, bsums, N, E);
    tg_fill<<<dim3((E + 255) / 256), dim3(256), 0, stream>>>(srcI, dstI, rowptr, cursor, col, E);
    // 4. GCN layers: hwpb = bf16((h@W)*dinv); h planes = relu(dinv*sum + b)
    for (int l = 0; l < 3; ++l) {
        tg_gemm_gcn<<<dim3(GB), dim3(256), 0, stream>>>(hh, hl, Bth[l + 1], Btl[l + 1], dinv, hwpb);
        tg_aggregate_bf<<<dim3((N + 3) / 4), dim3(256), 0, stream>>>(hwpb, rowptr, col, dinv,
                                                                     b_g[l], hh, hl, N);
    }
    // 5. per-graph mean pool
    tg_ranges<<<dim3((G + 256) / 256), dim3(256), 0, stream>>>(batch, starts, N, G);
    tg_pool<<<dim3(G), dim3(256), 0, stream>>>(hh, hl, starts, pooled, G);
    // 6. classifier MLP
    tg_mlp<<<dim3((G * 256 + 255) / 256), dim3(256), 0, stream>>>(pooled, W_c0, b_c0, z0, G, 256, 256, 1);
    tg_mlp<<<dim3((G * H2 + 255) / 256), dim3(256), 0, stream>>>(z0, W_c1, b_c1, z1, G, 256, H2, 1);
    tg_mlp<<<dim3((G * Cc + 255) / 256), dim3(256), 0, stream>>>(z1, W_c2, b_c2, (float*)d_out, G, H2, Cc, 0);
}